// Round 1
// baseline (113.786 us; speedup 1.0000x reference)
//
#include <hip/hip_runtime.h>

// GATConv reduces algebraically to a permuted-column GEMM:
//   out[n, c] = sum_k x[n,k] * W[(c%8)*64 + c/8, k] + bias[c]
// because the reference's einsum contracts alpha over its softmax-normalized
// axis (sum == 1), making the whole attention block a multiply-by-one.
// N=4096, K=256, M=512 columns.

#define BM 64
#define BN 64
#define BK 32
#define TM 4
#define TN 4

__global__ __launch_bounds__(256) void gat_gemm(
    const float* __restrict__ x,    // [4096, 256]
    const float* __restrict__ W,    // [512, 256]
    const float* __restrict__ bias, // [512]
    float* __restrict__ out)        // [4096, 512]
{
    __shared__ float As[BK][BM + 4];  // k-major, +4 pad keeps float4 align & banks spread
    __shared__ float Bs[BK][BN + 4];

    const int tid = threadIdx.x;       // 0..255
    const int tx = tid & 15;           // output-col group
    const int ty = tid >> 4;           // output-row group
    const int rowBase = blockIdx.y * BM;
    const int colBase = blockIdx.x * BN;

    float acc[TM][TN] = {};

    for (int kb = 0; kb < 256; kb += BK) {
        // Stage A (x tile) and B (permuted W tile): 2048 floats each = 2 float4/thread
        #pragma unroll
        for (int l = 0; l < 2; ++l) {
            int f  = tid + l * 256;   // float4 index 0..511
            int r  = f >> 3;          // tile row 0..63
            int kq = f & 7;           // float4 within the 32-wide k slab
            float4 av = *(const float4*)&x[(rowBase + r) * 256 + kb + kq * 4];
            int col  = colBase + r;
            int wrow = ((col & 7) << 6) + (col >> 3);   // perm(c)
            float4 bv = *(const float4*)&W[wrow * 256 + kb + kq * 4];
            As[kq * 4 + 0][r] = av.x; As[kq * 4 + 1][r] = av.y;
            As[kq * 4 + 2][r] = av.z; As[kq * 4 + 3][r] = av.w;
            Bs[kq * 4 + 0][r] = bv.x; Bs[kq * 4 + 1][r] = bv.y;
            Bs[kq * 4 + 2][r] = bv.z; Bs[kq * 4 + 3][r] = bv.w;
        }
        __syncthreads();

        #pragma unroll
        for (int kk = 0; kk < BK; ++kk) {
            float4 a4 = *(const float4*)&As[kk][ty * TM];
            float4 b4 = *(const float4*)&Bs[kk][tx * TN];
            float a[4] = {a4.x, a4.y, a4.z, a4.w};
            float b[4] = {b4.x, b4.y, b4.z, b4.w};
            #pragma unroll
            for (int i = 0; i < TM; ++i)
                #pragma unroll
                for (int j = 0; j < TN; ++j)
                    acc[i][j] += a[i] * b[j];
        }
        __syncthreads();
    }

    #pragma unroll
    for (int i = 0; i < TM; ++i) {
        int row = rowBase + ty * TM + i;
        int col = colBase + tx * TN;
        float4 o;
        o.x = acc[i][0] + bias[col + 0];
        o.y = acc[i][1] + bias[col + 1];
        o.z = acc[i][2] + bias[col + 2];
        o.w = acc[i][3] + bias[col + 3];
        *(float4*)&out[row * 512 + col] = o;
    }
}

extern "C" void kernel_launch(void* const* d_in, const int* in_sizes, int n_in,
                              void* d_out, int out_size, void* d_ws, size_t ws_size,
                              hipStream_t stream) {
    // setup_inputs order: 0=adj (unused), 1=x, 2=W, 3=att_src (unused),
    //                     4=att_dst (unused), 5=bias
    const float* x    = (const float*)d_in[1];
    const float* W    = (const float*)d_in[2];
    const float* bias = (const float*)d_in[5];
    float* out        = (float*)d_out;

    dim3 grid(512 / BN, 4096 / BM);  // 8 x 64 = 512 blocks
    dim3 block(256);
    hipLaunchKernelGGL(gat_gemm, grid, block, 0, stream, x, W, bias, out);
}

// Round 2
// 103.187 us; speedup vs baseline: 1.1027x; 1.1027x over previous
//
#include <hip/hip_runtime.h>
#include <hip/hip_bf16.h>

// GATConv reduces algebraically to a permuted-column GEMM:
//   out[n, c] = sum_k x[n,k] * W[(c%8)*64 + c/8, k] + bias[c]
// (the reference einsum contracts alpha over its softmax axis -> sum == 1).
// N=4096, K=256, M=512. bf16 MFMA version: K=256 fits fully in LDS, so the
// kernel is stage -> one barrier -> 8 x mfma_f32_16x16x32_bf16 per tile.

typedef __attribute__((ext_vector_type(8))) short bf16x8;   // 8 bf16 (4 VGPRs)
typedef __attribute__((ext_vector_type(4))) float floatx4;  // MFMA accumulator

#define BM 64
#define BN 64
#define LDK 264   // row stride in bf16 elems: 264*2B = 528B = 132 dwords -> 4-bank/row advance, 16B-aligned rows

__device__ __forceinline__ short f2bf(float f) {
    union { __hip_bfloat16 h; short s; } u;
    u.h = __float2bfloat16(f);   // RNE
    return u.s;
}

__global__ __launch_bounds__(256) void gat_gemm(
    const float* __restrict__ x,    // [4096, 256]
    const float* __restrict__ W,    // [512, 256]
    const float* __restrict__ bias, // [512]
    float* __restrict__ out)        // [4096, 512]
{
    __shared__ short As[BM][LDK];   // x tile, bf16
    __shared__ short Bs[BN][LDK];   // permuted-W tile, bf16 (B^T row-major)

    const int tid = threadIdx.x;       // 0..255
    const int rowBase = blockIdx.y * BM;
    const int colBase = blockIdx.x * BN;

    // ---- stage: 64x256 fp32 -> bf16 into LDS, for both A and B ----
    // 64*256/4 = 4096 float4 per tile; 16 float4/thread each.
    #pragma unroll
    for (int l = 0; l < 16; ++l) {
        int f  = tid + l * 256;    // float4 index 0..4095
        int r  = f >> 6;           // tile row 0..63
        int c4 = f & 63;           // float4 within row (k/4)
        float4 av = *(const float4*)&x[(rowBase + r) * 256 + c4 * 4];
        short4 a; a.x = f2bf(av.x); a.y = f2bf(av.y); a.z = f2bf(av.z); a.w = f2bf(av.w);
        *(short4*)&As[r][c4 * 4] = a;

        int col  = colBase + r;
        int wrow = ((col & 7) << 6) + (col >> 3);    // perm(c)
        float4 bv = *(const float4*)&W[wrow * 256 + c4 * 4];
        short4 b; b.x = f2bf(bv.x); b.y = f2bf(bv.y); b.z = f2bf(bv.z); b.w = f2bf(bv.w);
        *(short4*)&Bs[r][c4 * 4] = b;
    }
    __syncthreads();

    // ---- compute: each wave owns a 16-row slab, 4 col tiles of 16 ----
    const int wave = tid >> 6;         // 0..3
    const int lane = tid & 63;
    const int mrow = lane & 15;        // row within A tile / col within B tile
    const int quad = lane >> 4;        // 0..3 -> k-subblock (input), row-subblock (output)
    const int arow = wave * 16 + mrow;

    floatx4 acc[4] = {floatx4{0,0,0,0}, floatx4{0,0,0,0},
                      floatx4{0,0,0,0}, floatx4{0,0,0,0}};

    #pragma unroll
    for (int kb = 0; kb < 8; ++kb) {
        int koff = kb * 32 + quad * 8;                 // bf16 elem offset, 16B-aligned
        bf16x8 afrag = *(const bf16x8*)&As[arow][koff];
        #pragma unroll
        for (int t = 0; t < 4; ++t) {
            bf16x8 bfrag = *(const bf16x8*)&Bs[t * 16 + mrow][koff];
            acc[t] = __builtin_amdgcn_mfma_f32_16x16x32_bf16(afrag, bfrag, acc[t], 0, 0, 0);
        }
    }

    // ---- epilogue: C/D layout col=lane&15, row=quad*4+reg ----
    #pragma unroll
    for (int t = 0; t < 4; ++t) {
        int col = colBase + t * 16 + mrow;
        float bv = bias[col];
        #pragma unroll
        for (int r = 0; r < 4; ++r) {
            int row = rowBase + wave * 16 + quad * 4 + r;
            out[row * 512 + col] = acc[t][r] + bv;
        }
    }
}

extern "C" void kernel_launch(void* const* d_in, const int* in_sizes, int n_in,
                              void* d_out, int out_size, void* d_ws, size_t ws_size,
                              hipStream_t stream) {
    // setup_inputs order: 0=adj (unused), 1=x, 2=W, 3=att_src (unused),
    //                     4=att_dst (unused), 5=bias
    const float* x    = (const float*)d_in[1];
    const float* W    = (const float*)d_in[2];
    const float* bias = (const float*)d_in[5];
    float* out        = (float*)d_out;

    dim3 grid(512 / BN, 4096 / BM);  // 8 x 64 = 512 blocks
    dim3 block(256);
    hipLaunchKernelGGL(gat_gemm, grid, block, 0, stream, x, W, bias, out);
}